// Round 3
// baseline (2253.629 us; speedup 1.0000x reference)
//
#include <hip/hip_runtime.h>
#include <cstdint>
#include <cstddef>

#define NNODES 50000
#define NEDGES 20000
#define NNZT   1600000
#define CCAT   1024   // 4*256 concat features
#define CIN    256
#define COUT   40

#define EBLK 313      // gatherx blocks per chunk (64 edges each)
#define NBLK 782      // scatter_h/castx blocks per chunk (64 nodes each)

typedef __attribute__((ext_vector_type(8))) short bf16x8;
typedef __attribute__((ext_vector_type(4))) float f32x4;

__device__ inline float bflo(unsigned u) { return __uint_as_float(u << 16); }
__device__ inline float bfhi(unsigned u) { return __uint_as_float(u & 0xffff0000u); }
__device__ inline unsigned short f2bf(float f) {
  unsigned u = __float_as_uint(f);
  u += 0x7fff + ((u >> 16) & 1);
  return (unsigned short)(u >> 16);
}
__device__ inline unsigned packbf(float a, float b) {
  return (unsigned)f2bf(a) | ((unsigned)f2bf(b) << 16);
}

// ---------------- CSR build ----------------

__global__ void count_k(const int* __restrict__ ni, const int* __restrict__ ei,
                        int* __restrict__ cnt_e, int* __restrict__ cnt_n) {
  int i = blockIdx.x * 256 + threadIdx.x;
  if (i < NNZT) {
    atomicAdd(&cnt_e[ei[i]], 1);
    atomicAdd(&cnt_n[ni[i]], 1);
  }
}

__global__ void scan_k(const int* __restrict__ cnt, int* __restrict__ off, int len) {
  __shared__ int sh[1024];
  int t = threadIdx.x;
  int C = (len + 1023) >> 10;
  int base = t * C;
  int s = 0;
  for (int j = 0; j < C; j++) { int i = base + j; if (i < len) s += cnt[i]; }
  sh[t] = s;
  __syncthreads();
  for (int d = 1; d < 1024; d <<= 1) {
    int v = (t >= d) ? sh[t - d] : 0;
    __syncthreads();
    sh[t] += v;
    __syncthreads();
  }
  int run = (t == 0) ? 0 : sh[t - 1];
  for (int j = 0; j < C; j++) {
    int i = base + j;
    if (i < len) { off[i] = run; run += cnt[i]; }
  }
  if (t == 1023) off[len] = sh[1023];
}

__global__ void fill_k(const int* __restrict__ ni, const int* __restrict__ ei,
                       const int* __restrict__ off_e, const int* __restrict__ off_n,
                       int* __restrict__ cur_e, int* __restrict__ cur_n,
                       int* __restrict__ adj_e, int* __restrict__ adj_n) {
  int i = blockIdx.x * 256 + threadIdx.x;
  if (i < NNZT) {
    int e = ei[i], n = ni[i];
    int p = atomicAdd(&cur_e[e], 1);
    adj_e[off_e[e] + p] = n;
    int q = atomicAdd(&cur_n[n], 1);
    adj_n[off_n[n] + q] = e;
  }
}

__global__ void deg_k(const int* __restrict__ off_e, const int* __restrict__ off_n,
                      float* __restrict__ de_inv, float* __restrict__ dv_is) {
  int i = blockIdx.x * 256 + threadIdx.x;
  if (i < NNODES) {
    int d = off_n[i + 1] - off_n[i];
    dv_is[i] = (d > 0) ? rsqrtf((float)d) : 0.f;
  }
  if (i < NEDGES) {
    int d = off_e[i + 1] - off_e[i];
    de_inv[i] = (d > 0) ? (1.f / (float)d) : 0.f;
  }
}

// ---------------- s1 = S * ones (bias-through-smooth) ----------------

__global__ void t1_k(const int* __restrict__ off_e, const int* __restrict__ adj_e,
                     const float* __restrict__ dv_is, const float* __restrict__ de_inv,
                     float* __restrict__ t1) {
  int e = blockIdx.x; int lane = threadIdx.x;
  int beg = off_e[e], end = off_e[e + 1];
  float s = 0.f;
  for (int j = beg + lane; j < end; j += 64) s += dv_is[adj_e[j]];
  for (int d = 32; d > 0; d >>= 1) s += __shfl_down(s, d);
  if (lane == 0) t1[e] = s * de_inv[e];
}

__global__ void s1_k(const int* __restrict__ off_n, const int* __restrict__ adj_n,
                     const float* __restrict__ t1, const float* __restrict__ dv_is,
                     float* __restrict__ s1) {
  int n = blockIdx.x; int lane = threadIdx.x;
  int beg = off_n[n], end = off_n[n + 1];
  float s = 0.f;
  for (int j = beg + lane; j < end; j += 64) s += t1[adj_n[j]];
  for (int d = 32; d > 0; d >>= 1) s += __shfl_down(s, d);
  if (lane == 0) s1[n] = s * dv_is[n];
}

// ---------------- castx: chunk-major xbc[c][n][32] = bf16(dv_is[n]*x) ----------------

__global__ __launch_bounds__(256) void castx_k(
    const float* __restrict__ x, const float* __restrict__ dv_is,
    unsigned short* __restrict__ xbc) {
  int c = blockIdx.y;
  int n = blockIdx.x * 64 + (threadIdx.x >> 2);
  if (n >= NNODES) return;
  int seg = threadIdx.x & 3;
  int br = c >> 3;
  int col = (c & 7) * 32 + seg * 8;
  const float* xp = x + ((size_t)br * NNODES + n) * CIN + col;
  float4 v0 = *(const float4*)xp;
  float4 v1 = *(const float4*)(xp + 4);
  float dv = dv_is[n];
  uint4 o;
  o.x = packbf(v0.x * dv, v0.y * dv);
  o.y = packbf(v0.z * dv, v0.w * dv);
  o.z = packbf(v1.x * dv, v1.y * dv);
  o.w = packbf(v1.z * dv, v1.w * dv);
  *(uint4*)(xbc + ((size_t)c * NNODES + n) * 32 + seg * 8) = o;
}

// W1t[br][n][k] = bf16(W1[br][k][n])
__global__ __launch_bounds__(256) void castw1_k(
    const float* __restrict__ W1, unsigned short* __restrict__ W1t) {
  int n = blockIdx.x, br = blockIdx.y, t = threadIdx.x;
  float v = W1[((size_t)br * CIN + t) * CIN + n];
  W1t[((size_t)br * CIN + n) * CIN + t] = f2bf(v);
}

// ---------------- edge gather, chunked + XCD-pinned ----------------
// ef[e][c*32+..] = de_inv[e] * sum_n xbc[c][n][..]

__global__ __launch_bounds__(256) void gatherx_k(
    const unsigned short* __restrict__ xbc, const int* __restrict__ off_e,
    const int* __restrict__ adj_e, const float* __restrict__ de_inv,
    unsigned short* __restrict__ ef) {
  int bx = blockIdx.x;
  int c = (bx & 7) + 8 * (bx / (8 * EBLK));   // chunk pinned to XCD = bx%8
  int eb = (bx >> 3) % EBLK;
  int e = eb * 64 + (threadIdx.x >> 2);
  if (e >= NEDGES) return;
  int seg = threadIdx.x & 3;
  const unsigned short* base = xbc + (size_t)c * NNODES * 32 + seg * 8;
  int beg = off_e[e], end = off_e[e + 1];
  float a0 = 0, a1 = 0, a2 = 0, a3 = 0, a4 = 0, a5 = 0, a6 = 0, a7 = 0;
  for (int j = beg; j < end; j++) {
    int n = adj_e[j];
    uint4 v = *(const uint4*)(base + (size_t)n * 32);
    a0 += bflo(v.x); a1 += bfhi(v.x);
    a2 += bflo(v.y); a3 += bfhi(v.y);
    a4 += bflo(v.z); a5 += bfhi(v.z);
    a6 += bflo(v.w); a7 += bfhi(v.w);
  }
  float sc = de_inv[e];
  uint4 o;
  o.x = packbf(a0 * sc, a1 * sc);
  o.y = packbf(a2 * sc, a3 * sc);
  o.z = packbf(a4 * sc, a5 * sc);
  o.w = packbf(a6 * sc, a7 * sc);
  *(uint4*)(ef + (size_t)e * CCAT + c * 32 + seg * 8) = o;
}

// ---------------- GEMM1 (MFMA bf16): g = ef @ W1, G chunk-major ----------------

__global__ __launch_bounds__(256) void gemm1_k(
    const unsigned short* __restrict__ ef,   // [E][1024] bf16 row-major
    const unsigned short* __restrict__ W1t,  // [4][256(n)][256(k)] bf16
    unsigned short* __restrict__ G) {        // [32][E][32] bf16 chunk-major
  int rb = blockIdx.x, cb = blockIdx.y, br = blockIdx.z;
  int t = threadIdx.x;
  int w = t >> 6, l = t & 63;
  __shared__ unsigned short As[64 * 40];
  __shared__ unsigned short Bs[64 * 40];
  f32x4 acc[4] = {};
  int row0 = rb * 64;
  int srow = t >> 2, seg = t & 3;
  bool aok = (row0 + srow) < NEDGES;
  const unsigned short* ap = ef + (size_t)(row0 + srow) * CCAT + br * 256 + seg * 8;
  const unsigned short* bp = W1t + ((size_t)br * CIN + cb * 64 + srow) * CIN + seg * 8;
  int m = l & 15, q = l >> 4;
  for (int k0 = 0; k0 < CIN; k0 += 32) {
    uint4 av = {0, 0, 0, 0};
    if (aok) av = *(const uint4*)(ap + k0);
    uint4 bv = *(const uint4*)(bp + k0);
    *(uint4*)&As[srow * 40 + seg * 8] = av;
    *(uint4*)&Bs[srow * 40 + seg * 8] = bv;
    __syncthreads();
    bf16x8 a = *(bf16x8*)&As[(w * 16 + m) * 40 + q * 8];
    #pragma unroll
    for (int c = 0; c < 4; c++) {
      bf16x8 b = *(bf16x8*)&Bs[(c * 16 + m) * 40 + q * 8];
      acc[c] = __builtin_amdgcn_mfma_f32_16x16x32_bf16(a, b, acc[c], 0, 0, 0);
    }
    __syncthreads();
  }
  #pragma unroll
  for (int c = 0; c < 4; c++) {
    int f = br * 256 + cb * 64 + c * 16 + m;   // output channel
    size_t cbase = (size_t)(f >> 5) * NEDGES;
    #pragma unroll
    for (int r = 0; r < 4; r++) {
      int row = row0 + w * 16 + q * 4 + r;
      if (row < NEDGES)
        G[(cbase + row) * 32 + (f & 31)] = f2bf(acc[c][r]);
    }
  }
}

// ---------------- node scatter + bias + relu, chunked + XCD-pinned ----------------

__global__ __launch_bounds__(256) void scatter_h_k(
    const unsigned short* __restrict__ G, const int* __restrict__ off_n,
    const int* __restrict__ adj_n, const float* __restrict__ dv_is,
    const float* __restrict__ s1, const float* __restrict__ b1,
    unsigned short* __restrict__ hid) {   // [32][N][32] chunk-major
  int bx = blockIdx.x;
  int c = (bx & 7) + 8 * (bx / (8 * NBLK));
  int nb = (bx >> 3) % NBLK;
  int n = nb * 64 + (threadIdx.x >> 2);
  if (n >= NNODES) return;
  int seg = threadIdx.x & 3;
  const unsigned short* base = G + (size_t)c * NEDGES * 32 + seg * 8;
  int beg = off_n[n], end = off_n[n + 1];
  float a0 = 0, a1 = 0, a2 = 0, a3 = 0, a4 = 0, a5 = 0, a6 = 0, a7 = 0;
  for (int j = beg; j < end; j++) {
    int e = adj_n[j];
    uint4 v = *(const uint4*)(base + (size_t)e * 32);
    a0 += bflo(v.x); a1 += bfhi(v.x);
    a2 += bflo(v.y); a3 += bfhi(v.y);
    a4 += bflo(v.z); a5 += bfhi(v.z);
    a6 += bflo(v.w); a7 += bfhi(v.w);
  }
  float wv = dv_is[n], sb = s1[n];
  const float* bp = b1 + c * 32 + seg * 8;
  float4 b0 = *(const float4*)bp;
  float4 b4 = *(const float4*)(bp + 4);
  float h0 = fmaxf(wv * a0 + sb * b0.x, 0.f);
  float h1 = fmaxf(wv * a1 + sb * b0.y, 0.f);
  float h2 = fmaxf(wv * a2 + sb * b0.z, 0.f);
  float h3 = fmaxf(wv * a3 + sb * b0.w, 0.f);
  float h4 = fmaxf(wv * a4 + sb * b4.x, 0.f);
  float h5 = fmaxf(wv * a5 + sb * b4.y, 0.f);
  float h6 = fmaxf(wv * a6 + sb * b4.z, 0.f);
  float h7 = fmaxf(wv * a7 + sb * b4.w, 0.f);
  uint4 o;
  o.x = packbf(h0, h1); o.y = packbf(h2, h3);
  o.z = packbf(h4, h5); o.w = packbf(h6, h7);
  *(uint4*)(hid + ((size_t)c * NNODES + n) * 32 + seg * 8) = o;
}

// ---------------- GEMM2: u = hidden @ W2 + b2 (hidden chunk-major) ----------------

__global__ __launch_bounds__(256) void gemm2_k(
    const unsigned short* __restrict__ H, const float* __restrict__ W2,
    const float* __restrict__ b2, float* __restrict__ U) {
  int nb = blockIdx.x;
  int t = threadIdx.x;
  int r = t & 127, ch = t >> 7;
  __shared__ float Hs[64][257];
  __shared__ float Ws[64][40];
  float acc0[20] = {}, acc1[20] = {};
  int n0 = nb * 256;
  for (int k0 = 0; k0 < CCAT; k0 += 64) {
    #pragma unroll
    for (int i = 0; i < 8; i++) {
      int li = i * 256 + t;
      int row = li >> 3, kv = li & 7;
      uint4 v = {0, 0, 0, 0};
      int n = n0 + row;
      int chunk = (k0 >> 5) + (kv >> 2);
      if (n < NNODES) v = *(const uint4*)(H + ((size_t)chunk * NNODES + n) * 32 + (kv & 3) * 8);
      int kb = kv * 8;
      Hs[kb + 0][row] = bflo(v.x); Hs[kb + 1][row] = bfhi(v.x);
      Hs[kb + 2][row] = bflo(v.y); Hs[kb + 3][row] = bfhi(v.y);
      Hs[kb + 4][row] = bflo(v.z); Hs[kb + 5][row] = bfhi(v.z);
      Hs[kb + 6][row] = bflo(v.w); Hs[kb + 7][row] = bfhi(v.w);
    }
    #pragma unroll
    for (int i = 0; i < 10; i++) {
      int li = i * 256 + t;
      int k = li / 40, o2 = li - k * 40;
      Ws[k][o2] = W2[(size_t)(k0 + k) * COUT + o2];
    }
    __syncthreads();
    #pragma unroll 4
    for (int k = 0; k < 64; k++) {
      float h0 = Hs[k][r];
      float h1 = Hs[k][r + 128];
      const float* wr = &Ws[k][ch * 20];
      #pragma unroll
      for (int i = 0; i < 5; i++) {
        float4 wv = *(const float4*)(wr + i * 4);
        acc0[i * 4 + 0] += h0 * wv.x; acc0[i * 4 + 1] += h0 * wv.y;
        acc0[i * 4 + 2] += h0 * wv.z; acc0[i * 4 + 3] += h0 * wv.w;
        acc1[i * 4 + 0] += h1 * wv.x; acc1[i * 4 + 1] += h1 * wv.y;
        acc1[i * 4 + 2] += h1 * wv.z; acc1[i * 4 + 3] += h1 * wv.w;
      }
    }
    __syncthreads();
  }
  int n_a = n0 + r, n_b = n0 + r + 128;
  if (n_a < NNODES) {
    #pragma unroll
    for (int j = 0; j < 20; j++) {
      int o2 = ch * 20 + j;
      U[(size_t)n_a * COUT + o2] = acc0[j] + b2[o2];
    }
  }
  if (n_b < NNODES) {
    #pragma unroll
    for (int j = 0; j < 20; j++) {
      int o2 = ch * 20 + j;
      U[(size_t)n_b * COUT + o2] = acc1[j] + b2[o2];
    }
  }
}

// ---------------- final smooth (40 channels, fp32) ----------------

__global__ __launch_bounds__(256) void gather_u_k(
    const float* __restrict__ U, const int* __restrict__ off_e,
    const int* __restrict__ adj_e, const float* __restrict__ dv_is,
    const float* __restrict__ de_inv, float* __restrict__ ef2) {
  int e = blockIdx.x;
  int t = threadIdx.x;
  int w = t >> 6, lane = t & 63;
  __shared__ float red[4][COUT];
  float acc = 0.f;
  int beg = off_e[e], end = off_e[e + 1];
  if (lane < COUT) {
    for (int j = beg + w; j < end; j += 4) {
      int n = adj_e[j];
      acc += dv_is[n] * U[(size_t)n * COUT + lane];
    }
    red[w][lane] = acc;
  }
  __syncthreads();
  if (t < COUT) {
    float s = red[0][t] + red[1][t] + red[2][t] + red[3][t];
    ef2[(size_t)e * COUT + t] = s * de_inv[e];
  }
}

__global__ __launch_bounds__(256) void scatter_out_k(
    const float* __restrict__ ef2, const int* __restrict__ off_n,
    const int* __restrict__ adj_n, const float* __restrict__ dv_is,
    float* __restrict__ out) {
  int n = blockIdx.x;
  int t = threadIdx.x;
  int w = t >> 6, lane = t & 63;
  __shared__ float red[4][COUT];
  float acc = 0.f;
  int beg = off_n[n], end = off_n[n + 1];
  if (lane < COUT) {
    for (int j = beg + w; j < end; j += 4) {
      acc += ef2[(size_t)adj_n[j] * COUT + lane];
    }
    red[w][lane] = acc;
  }
  __syncthreads();
  if (t < COUT) {
    out[(size_t)n * COUT + t] = dv_is[n] * (red[0][t] + red[1][t] + red[2][t] + red[3][t]);
  }
}

// ---------------- launch ----------------

extern "C" void kernel_launch(void* const* d_in, const int* in_sizes, int n_in,
                              void* d_out, int out_size, void* d_ws, size_t ws_size,
                              hipStream_t stream) {
  const float* x  = (const float*)d_in[0];
  const float* W1 = (const float*)d_in[1];
  const float* b1 = (const float*)d_in[2];
  const float* W2 = (const float*)d_in[3];
  const float* b2 = (const float*)d_in[4];
  const int* ni   = (const int*)d_in[5];
  const int* ei   = (const int*)d_in[6];
  float* out = (float*)d_out;

  char* ws = (char*)d_ws;
  size_t o = 0;
  int* cnt_e = (int*)(ws + o); o += (size_t)NEDGES * 4;
  int* cnt_n = (int*)(ws + o); o += (size_t)NNODES * 4;
  int* cur_e = (int*)(ws + o); o += (size_t)NEDGES * 4;
  int* cur_n = (int*)(ws + o); o += (size_t)NNODES * 4;
  int* off_e = (int*)(ws + o); o += (size_t)(NEDGES + 1) * 4; o = (o + 255) & ~(size_t)255;
  int* off_n = (int*)(ws + o); o += (size_t)(NNODES + 1) * 4; o = (o + 255) & ~(size_t)255;
  float* de_inv = (float*)(ws + o); o += (size_t)NEDGES * 4;
  float* dv_is  = (float*)(ws + o); o += (size_t)NNODES * 4;
  float* t1     = (float*)(ws + o); o += (size_t)NEDGES * 4;
  float* s1     = (float*)(ws + o); o += (size_t)NNODES * 4; o = (o + 255) & ~(size_t)255;
  int* adj_e = (int*)(ws + o); o += (size_t)NNZT * 4;
  int* adj_n = (int*)(ws + o); o += (size_t)NNZT * 4; o = (o + 255) & ~(size_t)255;
  unsigned short* W1t = (unsigned short*)(ws + o); o += (size_t)4 * CIN * CIN * 2; o = (o + 255) & ~(size_t)255;
  // regionA: xbc [32][N][32] bf16 chunk-major; reused as hidden [32][N][32]
  unsigned short* xbc    = (unsigned short*)(ws + o);
  unsigned short* hidden = xbc;
  o += (size_t)NNODES * CCAT * 2; o = (o + 255) & ~(size_t)255;
  // regionB: ef [E][1024] bf16 row-major; later u [N][40] f32 + ef2 [E][40] f32
  unsigned short* ef = (unsigned short*)(ws + o);
  float* u   = (float*)ef;
  float* ef2 = (float*)((char*)ef + (size_t)NNODES * COUT * 4);
  o += (size_t)NEDGES * CCAT * 2; o = (o + 255) & ~(size_t)255;
  // regionC: G [32][E][32] bf16 chunk-major
  unsigned short* g = (unsigned short*)(ws + o);
  o += (size_t)NEDGES * CCAT * 2;

  hipMemsetAsync(cnt_e, 0, (size_t)(NEDGES + NNODES) * 2 * sizeof(int), stream);
  count_k<<<(NNZT + 255) / 256, 256, 0, stream>>>(ni, ei, cnt_e, cnt_n);
  scan_k<<<1, 1024, 0, stream>>>(cnt_e, off_e, NEDGES);
  scan_k<<<1, 1024, 0, stream>>>(cnt_n, off_n, NNODES);
  fill_k<<<(NNZT + 255) / 256, 256, 0, stream>>>(ni, ei, off_e, off_n, cur_e, cur_n, adj_e, adj_n);
  deg_k<<<(NNODES + 255) / 256, 256, 0, stream>>>(off_e, off_n, de_inv, dv_is);
  castx_k<<<dim3(NBLK, 32), 256, 0, stream>>>(x, dv_is, xbc);
  castw1_k<<<dim3(CIN, 4), 256, 0, stream>>>(W1, W1t);
  t1_k<<<NEDGES, 64, 0, stream>>>(off_e, adj_e, dv_is, de_inv, t1);
  s1_k<<<NNODES, 64, 0, stream>>>(off_n, adj_n, t1, dv_is, s1);
  gatherx_k<<<32 * EBLK, 256, 0, stream>>>(xbc, off_e, adj_e, de_inv, ef);
  gemm1_k<<<dim3((NEDGES + 63) / 64, 4, 4), 256, 0, stream>>>(ef, W1t, g);
  scatter_h_k<<<32 * NBLK, 256, 0, stream>>>(g, off_n, adj_n, dv_is, s1, b1, hidden);
  gemm2_k<<<(NNODES + 255) / 256, 256, 0, stream>>>(hidden, W2, b2, u);
  gather_u_k<<<NEDGES, 256, 0, stream>>>(u, off_e, adj_e, dv_is, de_inv, ef2);
  scatter_out_k<<<NNODES, 256, 0, stream>>>(ef2, off_n, adj_n, dv_is, out);
}

// Round 4
// 1937.807 us; speedup vs baseline: 1.1630x; 1.1630x over previous
//
#include <hip/hip_runtime.h>
#include <cstdint>
#include <cstddef>

#define NNODES 50000
#define NEDGES 20000
#define NNZT   1600000
#define CCAT   1024   // 4*256 concat features
#define CIN    256
#define COUT   40

typedef __attribute__((ext_vector_type(8))) short bf16x8;
typedef __attribute__((ext_vector_type(4))) float f32x4;

__device__ inline float bflo(unsigned u) { return __uint_as_float(u << 16); }
__device__ inline float bfhi(unsigned u) { return __uint_as_float(u & 0xffff0000u); }
__device__ inline float bfs(unsigned short u) { return __uint_as_float((unsigned)u << 16); }
__device__ inline unsigned short f2bf(float f) {
  unsigned u = __float_as_uint(f);
  u += 0x7fff + ((u >> 16) & 1);
  return (unsigned short)(u >> 16);
}
__device__ inline unsigned packbf(float a, float b) {
  return (unsigned)f2bf(a) | ((unsigned)f2bf(b) << 16);
}

// ---------------- CSR build ----------------

__global__ void count_k(const int* __restrict__ ni, const int* __restrict__ ei,
                        int* __restrict__ cnt_e, int* __restrict__ cnt_n) {
  int i = blockIdx.x * 256 + threadIdx.x;
  if (i < NNZT) {
    atomicAdd(&cnt_e[ei[i]], 1);
    atomicAdd(&cnt_n[ni[i]], 1);
  }
}

__global__ void scan_k(const int* __restrict__ cnt, int* __restrict__ off, int len) {
  __shared__ int sh[1024];
  int t = threadIdx.x;
  int C = (len + 1023) >> 10;
  int base = t * C;
  int s = 0;
  for (int j = 0; j < C; j++) { int i = base + j; if (i < len) s += cnt[i]; }
  sh[t] = s;
  __syncthreads();
  for (int d = 1; d < 1024; d <<= 1) {
    int v = (t >= d) ? sh[t - d] : 0;
    __syncthreads();
    sh[t] += v;
    __syncthreads();
  }
  int run = (t == 0) ? 0 : sh[t - 1];
  for (int j = 0; j < C; j++) {
    int i = base + j;
    if (i < len) { off[i] = run; run += cnt[i]; }
  }
  if (t == 1023) off[len] = sh[1023];
}

__global__ void fill_k(const int* __restrict__ ni, const int* __restrict__ ei,
                       const int* __restrict__ off_e, const int* __restrict__ off_n,
                       int* __restrict__ cur_e, int* __restrict__ cur_n,
                       int* __restrict__ adj_e, int* __restrict__ adj_n) {
  int i = blockIdx.x * 256 + threadIdx.x;
  if (i < NNZT) {
    int e = ei[i], n = ni[i];
    int p = atomicAdd(&cur_e[e], 1);
    adj_e[off_e[e] + p] = n;
    int q = atomicAdd(&cur_n[n], 1);
    adj_n[off_n[n] + q] = e;
  }
}

__global__ void deg_k(const int* __restrict__ off_e, const int* __restrict__ off_n,
                      float* __restrict__ de_inv, float* __restrict__ dv_is) {
  int i = blockIdx.x * 256 + threadIdx.x;
  if (i < NNODES) {
    int d = off_n[i + 1] - off_n[i];
    dv_is[i] = (d > 0) ? rsqrtf((float)d) : 0.f;
  }
  if (i < NEDGES) {
    int d = off_e[i + 1] - off_e[i];
    de_inv[i] = (d > 0) ? (1.f / (float)d) : 0.f;
  }
}

// ---------------- s1 = S * ones (bias-through-smooth) ----------------

__global__ void t1_k(const int* __restrict__ off_e, const int* __restrict__ adj_e,
                     const float* __restrict__ dv_is, const float* __restrict__ de_inv,
                     float* __restrict__ t1) {
  int e = blockIdx.x; int lane = threadIdx.x;
  int beg = off_e[e], end = off_e[e + 1];
  float s = 0.f;
  for (int j = beg + lane; j < end; j += 64) s += dv_is[adj_e[j]];
  for (int d = 32; d > 0; d >>= 1) s += __shfl_down(s, d);
  if (lane == 0) t1[e] = s * de_inv[e];
}

__global__ void s1_k(const int* __restrict__ off_n, const int* __restrict__ adj_n,
                     const float* __restrict__ t1, const float* __restrict__ dv_is,
                     float* __restrict__ s1) {
  int n = blockIdx.x; int lane = threadIdx.x;
  int beg = off_n[n], end = off_n[n + 1];
  float s = 0.f;
  for (int j = beg + lane; j < end; j += 64) s += t1[adj_n[j]];
  for (int d = 32; d > 0; d >>= 1) s += __shfl_down(s, d);
  if (lane == 0) s1[n] = s * dv_is[n];
}

// ---------------- castx: xq[br][n][256] = bf16(dv_is[n]*x[br][n][:]) ----------------

__global__ __launch_bounds__(256) void castx_k(
    const float* __restrict__ x, const float* __restrict__ dv_is,
    unsigned short* __restrict__ xq) {
  int n = blockIdx.x;
  int t = threadIdx.x;
  int br = t >> 6, c4 = (t & 63) * 4;
  float dv = dv_is[n];
  float4 v = *(const float4*)(x + ((size_t)br * NNODES + n) * CIN + c4);
  ushort4 o;
  o.x = f2bf(v.x * dv); o.y = f2bf(v.y * dv);
  o.z = f2bf(v.z * dv); o.w = f2bf(v.w * dv);
  *(ushort4*)(xq + ((size_t)br * NNODES + n) * CIN + c4) = o;
}

// W1t[br][n][k] = bf16(W1[br][k][n])
__global__ __launch_bounds__(256) void castw1_k(
    const float* __restrict__ W1, unsigned short* __restrict__ W1t) {
  int n = blockIdx.x, br = blockIdx.y, t = threadIdx.x;
  float v = W1[((size_t)br * CIN + t) * CIN + n];
  W1t[((size_t)br * CIN + n) * CIN + t] = f2bf(v);
}

// ---------------- edge gather, branch-chunked (slab 25.6MB, L3-resident) ----------
// ef[e][br*256+c] = de_inv[e] * sum_{n in e} xq[br][n][c]

__global__ __launch_bounds__(256) void gatherx_k(
    const unsigned short* __restrict__ xq, const int* __restrict__ off_e,
    const int* __restrict__ adj_e, const float* __restrict__ de_inv,
    unsigned short* __restrict__ ef) {
  int br = blockIdx.y;
  int e = blockIdx.x * 8 + (threadIdx.x >> 5);
  int lane = threadIdx.x & 31;
  const unsigned short* base = xq + (size_t)br * NNODES * CIN + lane * 8;
  int beg = off_e[e], end = off_e[e + 1];
  float a0 = 0, a1 = 0, a2 = 0, a3 = 0, a4 = 0, a5 = 0, a6 = 0, a7 = 0;
  for (int j = beg; j < end; j++) {
    int n = adj_e[j];
    uint4 v = *(const uint4*)(base + (size_t)n * CIN);
    a0 += bflo(v.x); a1 += bfhi(v.x);
    a2 += bflo(v.y); a3 += bfhi(v.y);
    a4 += bflo(v.z); a5 += bfhi(v.z);
    a6 += bflo(v.w); a7 += bfhi(v.w);
  }
  float sc = de_inv[e];
  uint4 o;
  o.x = packbf(a0 * sc, a1 * sc);
  o.y = packbf(a2 * sc, a3 * sc);
  o.z = packbf(a4 * sc, a5 * sc);
  o.w = packbf(a6 * sc, a7 * sc);
  *(uint4*)(ef + (size_t)e * CCAT + br * 256 + lane * 8) = o;
}

// ---------------- GEMM1 (MFMA bf16): G[br][e][256] = ef[e][br] @ W1[br] --------

__global__ __launch_bounds__(256) void gemm1_k(
    const unsigned short* __restrict__ ef,   // [E][1024] bf16 row-major
    const unsigned short* __restrict__ W1t,  // [4][256(n)][256(k)] bf16
    unsigned short* __restrict__ G) {        // [4][E][256] bf16 branch-major
  int rb = blockIdx.x, cb = blockIdx.y, br = blockIdx.z;
  int t = threadIdx.x;
  int w = t >> 6, l = t & 63;
  __shared__ unsigned short As[64 * 40];
  __shared__ unsigned short Bs[64 * 40];
  f32x4 acc[4] = {};
  int row0 = rb * 64;
  int srow = t >> 2, seg = t & 3;
  bool aok = (row0 + srow) < NEDGES;
  const unsigned short* ap = ef + (size_t)(row0 + srow) * CCAT + br * 256 + seg * 8;
  const unsigned short* bp = W1t + ((size_t)br * CIN + cb * 64 + srow) * CIN + seg * 8;
  int m = l & 15, q = l >> 4;
  for (int k0 = 0; k0 < CIN; k0 += 32) {
    uint4 av = {0, 0, 0, 0};
    if (aok) av = *(const uint4*)(ap + k0);
    uint4 bv = *(const uint4*)(bp + k0);
    *(uint4*)&As[srow * 40 + seg * 8] = av;
    *(uint4*)&Bs[srow * 40 + seg * 8] = bv;
    __syncthreads();
    bf16x8 a = *(bf16x8*)&As[(w * 16 + m) * 40 + q * 8];
    #pragma unroll
    for (int c = 0; c < 4; c++) {
      bf16x8 b = *(bf16x8*)&Bs[(c * 16 + m) * 40 + q * 8];
      acc[c] = __builtin_amdgcn_mfma_f32_16x16x32_bf16(a, b, acc[c], 0, 0, 0);
    }
    __syncthreads();
  }
  #pragma unroll
  for (int c = 0; c < 4; c++) {
    int f = cb * 64 + c * 16 + m;   // within-branch channel
    #pragma unroll
    for (int r = 0; r < 4; r++) {
      int row = row0 + w * 16 + q * 4 + r;
      if (row < NEDGES)
        G[((size_t)br * NEDGES + row) * 256 + f] = f2bf(acc[c][r]);
    }
  }
}

// ---------------- node scatter + bias + relu, branch-chunked (slab 10.2MB) -----

__global__ __launch_bounds__(256) void scatter_h_k(
    const unsigned short* __restrict__ G, const int* __restrict__ off_n,
    const int* __restrict__ adj_n, const float* __restrict__ dv_is,
    const float* __restrict__ s1, const float* __restrict__ b1,
    unsigned short* __restrict__ hid) {   // [4][N][256] branch-major
  int br = blockIdx.y;
  int n = blockIdx.x * 8 + (threadIdx.x >> 5);
  int lane = threadIdx.x & 31;
  const unsigned short* base = G + (size_t)br * NEDGES * 256 + lane * 8;
  int beg = off_n[n], end = off_n[n + 1];
  float a0 = 0, a1 = 0, a2 = 0, a3 = 0, a4 = 0, a5 = 0, a6 = 0, a7 = 0;
  for (int j = beg; j < end; j++) {
    int e = adj_n[j];
    uint4 v = *(const uint4*)(base + (size_t)e * 256);
    a0 += bflo(v.x); a1 += bfhi(v.x);
    a2 += bflo(v.y); a3 += bfhi(v.y);
    a4 += bflo(v.z); a5 += bfhi(v.z);
    a6 += bflo(v.w); a7 += bfhi(v.w);
  }
  float wv = dv_is[n], sb = s1[n];
  const float* bp = b1 + br * 256 + lane * 8;
  float4 b0 = *(const float4*)bp;
  float4 b4 = *(const float4*)(bp + 4);
  float h0 = fmaxf(wv * a0 + sb * b0.x, 0.f);
  float h1 = fmaxf(wv * a1 + sb * b0.y, 0.f);
  float h2 = fmaxf(wv * a2 + sb * b0.z, 0.f);
  float h3 = fmaxf(wv * a3 + sb * b0.w, 0.f);
  float h4 = fmaxf(wv * a4 + sb * b4.x, 0.f);
  float h5 = fmaxf(wv * a5 + sb * b4.y, 0.f);
  float h6 = fmaxf(wv * a6 + sb * b4.z, 0.f);
  float h7 = fmaxf(wv * a7 + sb * b4.w, 0.f);
  uint4 o;
  o.x = packbf(h0, h1); o.y = packbf(h2, h3);
  o.z = packbf(h4, h5); o.w = packbf(h6, h7);
  *(uint4*)(hid + ((size_t)br * NNODES + n) * 256 + lane * 8) = o;
}

// ---------------- GEMM2: u = hidden @ W2 + b2 (hidden branch-major, U bf16) ----

__global__ __launch_bounds__(256) void gemm2_k(
    const unsigned short* __restrict__ H, const float* __restrict__ W2,
    const float* __restrict__ b2, unsigned short* __restrict__ U) {
  int nb = blockIdx.x;
  int t = threadIdx.x;
  int r = t & 127, ch = t >> 7;
  __shared__ float Hs[64][257];
  __shared__ float Ws[64][40];
  float acc0[20] = {}, acc1[20] = {};
  int n0 = nb * 256;
  for (int k0 = 0; k0 < CCAT; k0 += 64) {
    int br = k0 >> 8, kin = k0 & 255;
    #pragma unroll
    for (int i = 0; i < 8; i++) {
      int li = i * 256 + t;
      int row = li >> 3, kv = li & 7;
      uint4 v = {0, 0, 0, 0};
      int n = n0 + row;
      if (n < NNODES) v = *(const uint4*)(H + ((size_t)br * NNODES + n) * 256 + kin + kv * 8);
      int kb = kv * 8;
      Hs[kb + 0][row] = bflo(v.x); Hs[kb + 1][row] = bfhi(v.x);
      Hs[kb + 2][row] = bflo(v.y); Hs[kb + 3][row] = bfhi(v.y);
      Hs[kb + 4][row] = bflo(v.z); Hs[kb + 5][row] = bfhi(v.z);
      Hs[kb + 6][row] = bflo(v.w); Hs[kb + 7][row] = bfhi(v.w);
    }
    #pragma unroll
    for (int i = 0; i < 10; i++) {
      int li = i * 256 + t;
      int k = li / 40, o2 = li - k * 40;
      Ws[k][o2] = W2[(size_t)(k0 + k) * COUT + o2];
    }
    __syncthreads();
    #pragma unroll 4
    for (int k = 0; k < 64; k++) {
      float h0 = Hs[k][r];
      float h1 = Hs[k][r + 128];
      const float* wr = &Ws[k][ch * 20];
      #pragma unroll
      for (int i = 0; i < 5; i++) {
        float4 wv = *(const float4*)(wr + i * 4);
        acc0[i * 4 + 0] += h0 * wv.x; acc0[i * 4 + 1] += h0 * wv.y;
        acc0[i * 4 + 2] += h0 * wv.z; acc0[i * 4 + 3] += h0 * wv.w;
        acc1[i * 4 + 0] += h1 * wv.x; acc1[i * 4 + 1] += h1 * wv.y;
        acc1[i * 4 + 2] += h1 * wv.z; acc1[i * 4 + 3] += h1 * wv.w;
      }
    }
    __syncthreads();
  }
  int n_a = n0 + r, n_b = n0 + r + 128;
  if (n_a < NNODES) {
    #pragma unroll
    for (int j = 0; j < 20; j++) {
      int o2 = ch * 20 + j;
      U[(size_t)n_a * COUT + o2] = f2bf(acc0[j] + b2[o2]);
    }
  }
  if (n_b < NNODES) {
    #pragma unroll
    for (int j = 0; j < 20; j++) {
      int o2 = ch * 20 + j;
      U[(size_t)n_b * COUT + o2] = f2bf(acc1[j] + b2[o2]);
    }
  }
}

// ---------------- final smooth (40 channels; U bf16, 4MB table) ----------------

__global__ __launch_bounds__(256) void gather_u_k(
    const unsigned short* __restrict__ U, const int* __restrict__ off_e,
    const int* __restrict__ adj_e, const float* __restrict__ dv_is,
    const float* __restrict__ de_inv, float* __restrict__ ef2) {
  int e = blockIdx.x;
  int t = threadIdx.x;
  int w = t >> 6, lane = t & 63;
  __shared__ float red[4][COUT];
  float acc = 0.f;
  int beg = off_e[e], end = off_e[e + 1];
  if (lane < COUT) {
    for (int j = beg + w; j < end; j += 4) {
      int n = adj_e[j];
      acc += dv_is[n] * bfs(U[(size_t)n * COUT + lane]);
    }
    red[w][lane] = acc;
  }
  __syncthreads();
  if (t < COUT) {
    float s = red[0][t] + red[1][t] + red[2][t] + red[3][t];
    ef2[(size_t)e * COUT + t] = s * de_inv[e];
  }
}

__global__ __launch_bounds__(256) void scatter_out_k(
    const float* __restrict__ ef2, const int* __restrict__ off_n,
    const int* __restrict__ adj_n, const float* __restrict__ dv_is,
    float* __restrict__ out) {
  int n = blockIdx.x;
  int t = threadIdx.x;
  int w = t >> 6, lane = t & 63;
  __shared__ float red[4][COUT];
  float acc = 0.f;
  int beg = off_n[n], end = off_n[n + 1];
  if (lane < COUT) {
    for (int j = beg + w; j < end; j += 4) {
      acc += ef2[(size_t)adj_n[j] * COUT + lane];
    }
    red[w][lane] = acc;
  }
  __syncthreads();
  if (t < COUT) {
    out[(size_t)n * COUT + t] = dv_is[n] * (red[0][t] + red[1][t] + red[2][t] + red[3][t]);
  }
}

// ---------------- launch ----------------

extern "C" void kernel_launch(void* const* d_in, const int* in_sizes, int n_in,
                              void* d_out, int out_size, void* d_ws, size_t ws_size,
                              hipStream_t stream) {
  const float* x  = (const float*)d_in[0];
  const float* W1 = (const float*)d_in[1];
  const float* b1 = (const float*)d_in[2];
  const float* W2 = (const float*)d_in[3];
  const float* b2 = (const float*)d_in[4];
  const int* ni   = (const int*)d_in[5];
  const int* ei   = (const int*)d_in[6];
  float* out = (float*)d_out;

  char* ws = (char*)d_ws;
  size_t o = 0;
  int* cnt_e = (int*)(ws + o); o += (size_t)NEDGES * 4;
  int* cnt_n = (int*)(ws + o); o += (size_t)NNODES * 4;
  int* cur_e = (int*)(ws + o); o += (size_t)NEDGES * 4;
  int* cur_n = (int*)(ws + o); o += (size_t)NNODES * 4;
  int* off_e = (int*)(ws + o); o += (size_t)(NEDGES + 1) * 4; o = (o + 255) & ~(size_t)255;
  int* off_n = (int*)(ws + o); o += (size_t)(NNODES + 1) * 4; o = (o + 255) & ~(size_t)255;
  float* de_inv = (float*)(ws + o); o += (size_t)NEDGES * 4;
  float* dv_is  = (float*)(ws + o); o += (size_t)NNODES * 4;
  float* t1     = (float*)(ws + o); o += (size_t)NEDGES * 4;
  float* s1     = (float*)(ws + o); o += (size_t)NNODES * 4; o = (o + 255) & ~(size_t)255;
  int* adj_e = (int*)(ws + o); o += (size_t)NNZT * 4;
  int* adj_n = (int*)(ws + o); o += (size_t)NNZT * 4; o = (o + 255) & ~(size_t)255;
  unsigned short* W1t = (unsigned short*)(ws + o); o += (size_t)4 * CIN * CIN * 2; o = (o + 255) & ~(size_t)255;
  // regionA: xq [4][N][256] bf16 branch-major; reused as hidden [4][N][256]
  unsigned short* xq     = (unsigned short*)(ws + o);
  unsigned short* hidden = xq;
  o += (size_t)NNODES * CCAT * 2; o = (o + 255) & ~(size_t)255;
  // regionB: ef [E][1024] bf16 row-major; later U [N][40] bf16 + ef2 [E][40] f32
  unsigned short* ef = (unsigned short*)(ws + o);
  unsigned short* u  = ef;
  float* ef2 = (float*)((char*)ef + (((size_t)NNODES * COUT * 2 + 255) & ~(size_t)255));
  o += (size_t)NEDGES * CCAT * 2; o = (o + 255) & ~(size_t)255;
  // regionC: G [4][E][256] bf16 branch-major
  unsigned short* g = (unsigned short*)(ws + o);
  o += (size_t)NEDGES * CCAT * 2;

  hipMemsetAsync(cnt_e, 0, (size_t)(NEDGES + NNODES) * 2 * sizeof(int), stream);
  count_k<<<(NNZT + 255) / 256, 256, 0, stream>>>(ni, ei, cnt_e, cnt_n);
  scan_k<<<1, 1024, 0, stream>>>(cnt_e, off_e, NEDGES);
  scan_k<<<1, 1024, 0, stream>>>(cnt_n, off_n, NNODES);
  fill_k<<<(NNZT + 255) / 256, 256, 0, stream>>>(ni, ei, off_e, off_n, cur_e, cur_n, adj_e, adj_n);
  deg_k<<<(NNODES + 255) / 256, 256, 0, stream>>>(off_e, off_n, de_inv, dv_is);
  castx_k<<<NNODES, 256, 0, stream>>>(x, dv_is, xq);
  castw1_k<<<dim3(CIN, 4), 256, 0, stream>>>(W1, W1t);
  t1_k<<<NEDGES, 64, 0, stream>>>(off_e, adj_e, dv_is, de_inv, t1);
  s1_k<<<NNODES, 64, 0, stream>>>(off_n, adj_n, t1, dv_is, s1);
  gatherx_k<<<dim3(NEDGES / 8, 4), 256, 0, stream>>>(xq, off_e, adj_e, de_inv, ef);
  gemm1_k<<<dim3((NEDGES + 63) / 64, 4, 4), 256, 0, stream>>>(ef, W1t, g);
  scatter_h_k<<<dim3(NNODES / 8, 4), 256, 0, stream>>>(g, off_n, adj_n, dv_is, s1, b1, hidden);
  gemm2_k<<<(NNODES + 255) / 256, 256, 0, stream>>>(hidden, W2, b2, u);
  gather_u_k<<<NEDGES, 256, 0, stream>>>(u, off_e, adj_e, dv_is, de_inv, ef2);
  scatter_out_k<<<NNODES, 256, 0, stream>>>(ef2, off_n, adj_n, dv_is, out);
}